// Round 1
// baseline (128.088 us; speedup 1.0000x reference)
//
#include <hip/hip_runtime.h>
#include <math.h>

#define B_ 2
#define N_ 1024
#define C_ 81
#define NFG 80            // foreground classes 1..80
#define DETS 100
#define CAND (N_ * NFG)   // 81920 per image
#define SORT_CAP 4096
#define SCORE_THRESH 0.05f
#define NMS_THRESH 0.5f
#define NEG_INF -1e30f
#define IMG_W_M1 1332.0f
#define IMG_H_M1 799.0f
#define XFORM_CLIP 4.135166556742356f   // log(1000/16)

// ---------------- device helpers ----------------

__device__ __forceinline__ void decode_box(const float* __restrict__ breg,
                                           const float* __restrict__ pbox,
                                           int row, int c, float* out) {
    float bx1 = pbox[row * 4 + 0];
    float by1 = pbox[row * 4 + 1];
    float bx2 = pbox[row * 4 + 2];
    float by2 = pbox[row * 4 + 3];
    float w  = bx2 - bx1 + 1.0f;
    float h  = by2 - by1 + 1.0f;
    float cx = bx1 + 0.5f * w;
    float cy = by1 + 0.5f * h;
    const float* r = breg + (size_t)row * (C_ * 4) + c * 4;
    float dx = r[0] / 10.0f;
    float dy = r[1] / 10.0f;
    float dw = fminf(r[2] / 5.0f, (float)XFORM_CLIP);
    float dh = fminf(r[3] / 5.0f, (float)XFORM_CLIP);
    float px = dx * w + cx;
    float py = dy * h + cy;
    float pw = expf(dw) * w;
    float ph = expf(dh) * h;
    float x1 = px - 0.5f * pw;
    float y1 = py - 0.5f * ph;
    float x2 = px + 0.5f * pw - 1.0f;
    float y2 = py + 0.5f * ph - 1.0f;
    out[0] = fminf(fmaxf(x1, 0.0f), IMG_W_M1);
    out[1] = fminf(fmaxf(y1, 0.0f), IMG_H_M1);
    out[2] = fminf(fmaxf(x2, 0.0f), IMG_W_M1);
    out[3] = fminf(fmaxf(y2, 0.0f), IMG_H_M1);
}

// ---------------- kernel 1: softmax (one wave per row) ----------------

__global__ __launch_bounds__(64) void softmax_k(const float* __restrict__ logits,
                                                float* __restrict__ prob,
                                                int* __restrict__ count) {
    int row  = blockIdx.x;
    int lane = threadIdx.x;
    if (row == 0 && lane == 0) { count[0] = 0; count[1] = 0; }
    const float* rp = logits + (size_t)row * C_;
    float v0 = rp[lane];
    float v1 = (lane + 64 < C_) ? rp[lane + 64] : -INFINITY;
    float m = fmaxf(v0, v1);
    #pragma unroll
    for (int off = 32; off; off >>= 1) m = fmaxf(m, __shfl_xor(m, off));
    float e0 = expf(v0 - m);
    float e1 = (lane + 64 < C_) ? expf(v1 - m) : 0.0f;
    float s = e0 + e1;
    #pragma unroll
    for (int off = 32; off; off >>= 1) s += __shfl_xor(s, off);
    prob[(size_t)row * C_ + lane] = e0 / s;
    if (lane + 64 < C_) prob[(size_t)row * C_ + lane + 64] = e1 / s;
}

// ---------------- kernel 2: per (image, class) greedy NMS ----------------

__global__ __launch_bounds__(256) void nms_k(const float* __restrict__ prob,
                                             const float* __restrict__ breg,
                                             const float* __restrict__ pbox,
                                             float* __restrict__ cand_s,
                                             int* __restrict__ cand_i,
                                             int* __restrict__ count) {
    __shared__ float skey[N_];
    __shared__ int   sidx[N_];
    __shared__ float sx1[N_], sy1[N_], sx2[N_], sy2[N_], sar[N_];
    __shared__ int   removed[N_];
    __shared__ int   mcount;

    int blk = blockIdx.x;
    int b   = blk / NFG;
    int c   = blk % NFG + 1;        // foreground class index 1..80
    int tid = threadIdx.x;

    if (tid == 0) mcount = 0;
    __syncthreads();

    int local = 0;
    for (int n = tid; n < N_; n += 256) {
        int row = b * N_ + n;
        float s = prob[(size_t)row * C_ + c];
        bool valid = s > SCORE_THRESH;
        skey[n] = valid ? s : NEG_INF;
        sidx[n] = n;
        if (valid) local++;
        float box[4];
        decode_box(breg, pbox, row, c, box);
        sx1[n] = box[0]; sy1[n] = box[1]; sx2[n] = box[2]; sy2[n] = box[3];
        sar[n] = (box[2] - box[0] + 1.0f) * (box[3] - box[1] + 1.0f);
        removed[n] = 0;
    }
    atomicAdd(&mcount, local);
    __syncthreads();
    int M = mcount;
    if (M == 0) return;

    // bitonic sort: descending score, ascending original index (stable-argsort match)
    for (int k = 2; k <= N_; k <<= 1) {
        for (int j = k >> 1; j > 0; j >>= 1) {
            for (int i = tid; i < N_; i += 256) {
                int l = i ^ j;
                if (l > i) {
                    float ki = skey[i], kl = skey[l];
                    int   ii = sidx[i], il = sidx[l];
                    bool iFirst = (ki > kl) || (ki == kl && ii < il);
                    bool asc = ((i & k) == 0);
                    if (iFirst != asc) {
                        skey[i] = kl; skey[l] = ki;
                        sidx[i] = il; sidx[l] = ii;
                    }
                }
            }
            __syncthreads();
        }
    }

    // sequential greedy NMS, parallel suppression
    for (int i = 0; i < M; ++i) {
        __syncthreads();
        if (!removed[i]) {
            int ni = sidx[i];
            float x1i = sx1[ni], y1i = sy1[ni], x2i = sx2[ni], y2i = sy2[ni], ai = sar[ni];
            for (int j = i + 1 + tid; j < M; j += 256) {
                if (!removed[j]) {
                    int nj = sidx[j];
                    float xx1 = fmaxf(x1i, sx1[nj]);
                    float yy1 = fmaxf(y1i, sy1[nj]);
                    float xx2 = fminf(x2i, sx2[nj]);
                    float yy2 = fminf(y2i, sy2[nj]);
                    float w = fmaxf(xx2 - xx1 + 1.0f, 0.0f);
                    float h = fmaxf(yy2 - yy1 + 1.0f, 0.0f);
                    float inter = w * h;
                    float iou = inter / (ai + sar[nj] - inter);
                    if (iou > NMS_THRESH) removed[j] = 1;
                }
            }
        }
    }
    __syncthreads();

    // append survivors to per-image candidate list
    for (int j = tid; j < M; j += 256) {
        if (!removed[j]) {
            int pos = atomicAdd(&count[b], 1);
            cand_s[(size_t)b * CAND + pos] = skey[j];
            cand_i[(size_t)b * CAND + pos] = sidx[j] * NFG + (c - 1);
        }
    }
}

// ---------------- kernel 3: per-image top-100 ----------------

__global__ __launch_bounds__(1024) void topk_k(float* __restrict__ cand_s,
                                               const int* __restrict__ cand_i,
                                               const int* __restrict__ count,
                                               const float* __restrict__ breg,
                                               const float* __restrict__ pbox,
                                               float* __restrict__ out) {
    __shared__ float skey[SORT_CAP];
    __shared__ int   sidx[SORT_CAP];
    __shared__ float rs[1024];
    __shared__ int   rf[1024];
    __shared__ int   rp[1024];

    int b   = blockIdx.x;
    int tid = threadIdx.x;
    int M   = count[b];
    float* cs = cand_s + (size_t)b * CAND;
    const int* ci = cand_i + (size_t)b * CAND;
    float* boxes_o  = out + (size_t)b * DETS * 4;
    float* scores_o = out + (size_t)B_ * DETS * 4 + (size_t)b * DETS;
    float* labels_o = out + (size_t)B_ * DETS * 4 + (size_t)B_ * DETS + (size_t)b * DETS;

    if (M <= SORT_CAP) {
        for (int i = tid; i < SORT_CAP; i += 1024) {
            skey[i] = (i < M) ? cs[i] : NEG_INF;
            sidx[i] = (i < M) ? ci[i] : 0x7fffffff;
        }
        __syncthreads();
        for (int k = 2; k <= SORT_CAP; k <<= 1) {
            for (int j = k >> 1; j > 0; j >>= 1) {
                for (int i = tid; i < SORT_CAP; i += 1024) {
                    int l = i ^ j;
                    if (l > i) {
                        float ki = skey[i], kl = skey[l];
                        int   ii = sidx[i], il = sidx[l];
                        bool iFirst = (ki > kl) || (ki == kl && ii < il);
                        bool asc = ((i & k) == 0);
                        if (iFirst != asc) {
                            skey[i] = kl; skey[l] = ki;
                            sidx[i] = il; sidx[l] = ii;
                        }
                    }
                }
                __syncthreads();
            }
        }
        if (tid < DETS) {
            float s = skey[tid];
            bool valid = s > SCORE_THRESH;
            float box[4] = {0.f, 0.f, 0.f, 0.f};
            float lab = -1.0f, sc = 0.0f;
            if (valid) {
                int fi = sidx[tid];
                int n = fi / NFG;
                int c = fi % NFG + 1;
                decode_box(breg, pbox, b * N_ + n, c, box);
                lab = (float)c; sc = s;
            }
            boxes_o[tid * 4 + 0] = box[0];
            boxes_o[tid * 4 + 1] = box[1];
            boxes_o[tid * 4 + 2] = box[2];
            boxes_o[tid * 4 + 3] = box[3];
            scores_o[tid] = sc;
            labels_o[tid] = lab;
        }
    } else {
        // fallback (M > SORT_CAP, vanishingly unlikely): repeated argmax
        for (int it = 0; it < DETS; ++it) {
            float bs = NEG_INF; int bf = 0x7fffffff; int bp = -1;
            for (int i = tid; i < M; i += 1024) {
                float s = cs[i]; int f = ci[i];
                if (s > bs || (s == bs && f < bf)) { bs = s; bf = f; bp = i; }
            }
            rs[tid] = bs; rf[tid] = bf; rp[tid] = bp;
            __syncthreads();
            for (int off = 512; off; off >>= 1) {
                if (tid < off) {
                    if (rs[tid + off] > rs[tid] ||
                        (rs[tid + off] == rs[tid] && rf[tid + off] < rf[tid])) {
                        rs[tid] = rs[tid + off]; rf[tid] = rf[tid + off]; rp[tid] = rp[tid + off];
                    }
                }
                __syncthreads();
            }
            if (tid == 0) {
                float s = rs[0];
                bool valid = s > SCORE_THRESH;
                float box[4] = {0.f, 0.f, 0.f, 0.f};
                float lab = -1.0f, sc = 0.0f;
                if (valid) {
                    int fi = rf[0];
                    int n = fi / NFG;
                    int c = fi % NFG + 1;
                    decode_box(breg, pbox, b * N_ + n, c, box);
                    lab = (float)c; sc = s;
                    cs[rp[0]] = NEG_INF;
                }
                boxes_o[it * 4 + 0] = box[0];
                boxes_o[it * 4 + 1] = box[1];
                boxes_o[it * 4 + 2] = box[2];
                boxes_o[it * 4 + 3] = box[3];
                scores_o[it] = sc;
                labels_o[it] = lab;
            }
            __syncthreads();
        }
    }
}

// ---------------- launch ----------------

extern "C" void kernel_launch(void* const* d_in, const int* in_sizes, int n_in,
                              void* d_out, int out_size, void* d_ws, size_t ws_size,
                              hipStream_t stream) {
    const float* logits = (const float*)d_in[0];   // [2048, 81]
    const float* breg   = (const float*)d_in[1];   // [2048, 324]
    const float* pbox   = (const float*)d_in[2];   // [2048, 4]
    float* out = (float*)d_out;                    // 800 boxes + 200 scores + 200 labels

    float* prob   = (float*)d_ws;                    // 2048*81 = 165888 floats
    float* cand_s = prob + (size_t)B_ * N_ * C_;     // B*81920 floats
    int*   cand_i = (int*)(cand_s + (size_t)B_ * CAND);
    int*   count  = (int*)(cand_i + (size_t)B_ * CAND);

    softmax_k<<<B_ * N_, 64, 0, stream>>>(logits, prob, count);
    nms_k<<<B_ * NFG, 256, 0, stream>>>(prob, breg, pbox, cand_s, cand_i, count);
    topk_k<<<B_, 1024, 0, stream>>>(cand_s, cand_i, count, breg, pbox, out);
}

// Round 2
// 56.597 us; speedup vs baseline: 2.2632x; 2.2632x over previous
//
#include <hip/hip_runtime.h>
#include <math.h>

#define B_ 2
#define N_ 1024
#define C_ 81
#define NFG 80            // foreground classes 1..80
#define DETS 100
#define CAND (N_ * NFG)   // 81920 per image
#define SCORE_THRESH 0.05f
#define NMS_THRESH 0.5f
#define NEG_INF -1e30f
#define IMG_W_M1 1332.0f
#define IMG_H_M1 799.0f
#define XFORM_CLIP 4.135166556742356f   // log(1000/16)
#define HB 192            // coarse score-histogram buckets
#define LCAP 512          // topk collection capacity

// ---------------- device helpers ----------------

__device__ __forceinline__ void decode_box(const float* __restrict__ breg,
                                           const float* __restrict__ pbox,
                                           int row, int c, float* out) {
    float bx1 = pbox[row * 4 + 0];
    float by1 = pbox[row * 4 + 1];
    float bx2 = pbox[row * 4 + 2];
    float by2 = pbox[row * 4 + 3];
    float w  = bx2 - bx1 + 1.0f;
    float h  = by2 - by1 + 1.0f;
    float cx = bx1 + 0.5f * w;
    float cy = by1 + 0.5f * h;
    const float* r = breg + (size_t)row * (C_ * 4) + c * 4;
    float dx = r[0] / 10.0f;
    float dy = r[1] / 10.0f;
    float dw = fminf(r[2] / 5.0f, (float)XFORM_CLIP);
    float dh = fminf(r[3] / 5.0f, (float)XFORM_CLIP);
    float px = dx * w + cx;
    float py = dy * h + cy;
    float pw = expf(dw) * w;
    float ph = expf(dh) * h;
    float x1 = px - 0.5f * pw;
    float y1 = py - 0.5f * ph;
    float x2 = px + 0.5f * pw - 1.0f;
    float y2 = py + 0.5f * ph - 1.0f;
    out[0] = fminf(fmaxf(x1, 0.0f), IMG_W_M1);
    out[1] = fminf(fmaxf(y1, 0.0f), IMG_H_M1);
    out[2] = fminf(fmaxf(x2, 0.0f), IMG_W_M1);
    out[3] = fminf(fmaxf(y2, 0.0f), IMG_H_M1);
}

// ---------------- kernel 1: softmax (one wave per row) ----------------

__global__ __launch_bounds__(64) void softmax_k(const float* __restrict__ logits,
                                                float* __restrict__ prob,
                                                int* __restrict__ count) {
    int row  = blockIdx.x;
    int lane = threadIdx.x;
    if (row == 0 && lane == 0) { count[0] = 0; count[1] = 0; }
    const float* rp = logits + (size_t)row * C_;
    float v0 = rp[lane];
    float v1 = (lane + 64 < C_) ? rp[lane + 64] : -INFINITY;
    float m = fmaxf(v0, v1);
    #pragma unroll
    for (int off = 32; off; off >>= 1) m = fmaxf(m, __shfl_xor(m, off));
    float e0 = expf(v0 - m);
    float e1 = (lane + 64 < C_) ? expf(v1 - m) : 0.0f;
    float s = e0 + e1;
    #pragma unroll
    for (int off = 32; off; off >>= 1) s += __shfl_xor(s, off);
    prob[(size_t)row * C_ + lane] = e0 / s;
    if (lane + 64 < C_) prob[(size_t)row * C_ + lane + 64] = e1 / s;
}

// ---------------- kernel 2: per (image, class) greedy NMS ----------------
// compact -> small bitonic sort -> barrier-free wave-0 greedy suppression

__global__ __launch_bounds__(256) void nms_k(const float* __restrict__ prob,
                                             const float* __restrict__ breg,
                                             const float* __restrict__ pbox,
                                             float* __restrict__ cand_s,
                                             int* __restrict__ cand_i,
                                             int* __restrict__ count) {
    __shared__ float skey[N_];
    __shared__ int   sidx[N_];
    __shared__ float sx1[N_], sy1[N_], sx2[N_], sy2[N_], sar[N_];
    __shared__ unsigned rembits[64];
    __shared__ int   mcount;

    int blk = blockIdx.x;
    int b   = blk / NFG;
    int c   = blk % NFG + 1;        // foreground class index 1..80
    int tid = threadIdx.x;

    if (tid == 0) mcount = 0;
    __syncthreads();

    // compact entries with score > thresh
    for (int n = tid; n < N_; n += 256) {
        float s = prob[(size_t)(b * N_ + n) * C_ + c];
        if (s > SCORE_THRESH) {
            int p = atomicAdd(&mcount, 1);
            skey[p] = s;
            sidx[p] = n;
        }
    }
    __syncthreads();
    int M = mcount;
    if (M == 0) return;   // uniform across block

    int P = 64;
    while (P < M) P <<= 1;
    for (int i = M + tid; i < P; i += 256) { skey[i] = NEG_INF; sidx[i] = 0x7fffffff; }
    __syncthreads();

    // bitonic sort over P: descending score, ascending original index
    for (int k = 2; k <= P; k <<= 1) {
        for (int j = k >> 1; j > 0; j >>= 1) {
            for (int i = tid; i < P; i += 256) {
                int l = i ^ j;
                if (l > i) {
                    float ki = skey[i], kl = skey[l];
                    int   ii = sidx[i], il = sidx[l];
                    bool iFirst = (ki > kl) || (ki == kl && ii < il);
                    bool asc = ((i & k) == 0);
                    if (iFirst != asc) {
                        skey[i] = kl; skey[l] = ki;
                        sidx[i] = il; sidx[l] = ii;
                    }
                }
            }
            __syncthreads();
        }
    }

    // decode boxes only for the M sorted candidates
    for (int i = tid; i < M; i += 256) {
        float box[4];
        decode_box(breg, pbox, b * N_ + sidx[i], c, box);
        sx1[i] = box[0]; sy1[i] = box[1]; sx2[i] = box[2]; sy2[i] = box[3];
        sar[i] = (box[2] - box[0] + 1.0f) * (box[3] - box[1] + 1.0f);
    }
    __syncthreads();

    // barrier-free greedy NMS in wave 0.
    // sorted position j is owned by lane (j&63), slot (j>>6); removed flags
    // live in per-lane register bitmask `my`.
    if (tid < 64) {
        int lane = tid;
        unsigned my = 0;
        for (int i = 0; i < M; ++i) {
            unsigned obits = __shfl(my, i & 63);
            bool kept = ((obits >> (i >> 6)) & 1u) == 0u;
            if (kept) {
                float x1i = sx1[i], y1i = sy1[i], x2i = sx2[i], y2i = sy2[i], ai = sar[i];
                for (int j = lane; j < M; j += 64) {
                    if (j > i && !((my >> (j >> 6)) & 1u)) {
                        float xx1 = fmaxf(x1i, sx1[j]);
                        float yy1 = fmaxf(y1i, sy1[j]);
                        float xx2 = fminf(x2i, sx2[j]);
                        float yy2 = fminf(y2i, sy2[j]);
                        float w = fmaxf(xx2 - xx1 + 1.0f, 0.0f);
                        float h = fmaxf(yy2 - yy1 + 1.0f, 0.0f);
                        float inter = w * h;
                        float iou = inter / (ai + sar[j] - inter);
                        if (iou > NMS_THRESH) my |= 1u << (j >> 6);
                    }
                }
            }
        }
        rembits[lane] = my;
    }
    __syncthreads();

    // append survivors to per-image candidate list
    for (int j = tid; j < M; j += 256) {
        if (!((rembits[j & 63] >> (j >> 6)) & 1u)) {
            int pos = atomicAdd(&count[b], 1);
            cand_s[(size_t)b * CAND + pos] = skey[j];
            cand_i[(size_t)b * CAND + pos] = sidx[j] * NFG + (c - 1);
        }
    }
}

// ---------------- kernel 3: per-image top-100 via histogram select ----------------

__global__ __launch_bounds__(256) void topk_k(float* __restrict__ cand_s,
                                              const int* __restrict__ cand_i,
                                              const int* __restrict__ count,
                                              const float* __restrict__ breg,
                                              const float* __restrict__ pbox,
                                              float* __restrict__ out) {
    __shared__ int   hist[HB];
    __shared__ float ls[LCAP];
    __shared__ int   lf[LCAP];
    __shared__ int   lcnt;
    __shared__ int   sel_t1;
    __shared__ float rs[256];
    __shared__ int   rf[256];
    __shared__ int   rp[256];

    int b   = blockIdx.x;
    int tid = threadIdx.x;
    int M   = count[b];
    float* cs = cand_s + (size_t)b * CAND;
    const int* ci = cand_i + (size_t)b * CAND;
    float* boxes_o  = out + (size_t)b * DETS * 4;
    float* scores_o = out + (size_t)B_ * DETS * 4 + (size_t)b * DETS;
    float* labels_o = out + (size_t)B_ * DETS * 4 + (size_t)B_ * DETS + (size_t)b * DETS;

    for (int i = tid; i < HB; i += 256) hist[i] = 0;
    if (tid == 0) lcnt = 0;
    __syncthreads();

    // coarse histogram on float bit pattern (monotonic for positive floats);
    // all candidate scores are in (0.05, 1.0] -> bits in [0x3D4CCCCE, 0x3F800000]
    for (int i = tid; i < M; i += 256) {
        unsigned bits = __float_as_uint(cs[i]);
        int cb = (int)((bits - 0x3D000000u) >> 18);
        if (cb > HB - 1) cb = HB - 1;
        atomicAdd(&hist[cb], 1);
    }
    __syncthreads();

    if (tid == 0) {
        int t = 0;
        if (M > DETS) {
            int acc = 0;
            for (int bi = HB - 1; bi >= 0; --bi) {
                if (acc + hist[bi] >= DETS) { t = bi; break; }
                acc += hist[bi];
            }
        }
        sel_t1 = t;
    }
    __syncthreads();
    int t1 = sel_t1;

    // collect all candidates at/above the boundary bucket
    for (int i = tid; i < M; i += 256) {
        float s = cs[i];
        unsigned bits = __float_as_uint(s);
        int cb = (int)((bits - 0x3D000000u) >> 18);
        if (cb > HB - 1) cb = HB - 1;
        if (cb >= t1) {
            int p = atomicAdd(&lcnt, 1);
            if (p < LCAP) { ls[p] = s; lf[p] = ci[i]; }
        }
    }
    __syncthreads();
    int L = lcnt;

    if (L <= LCAP) {
        // rank-by-counting: (score desc, flat index asc) is a strict total order
        for (int e = tid; e < L; e += 256) {
            float s = ls[e]; int f = lf[e];
            int r = 0;
            for (int q = 0; q < L; ++q) {
                float sq = ls[q]; int fq = lf[q];
                if (sq > s || (sq == s && fq < f)) r++;
            }
            if (r < DETS) {
                int n = f / NFG;
                int c = f % NFG + 1;
                float box[4];
                decode_box(breg, pbox, b * N_ + n, c, box);
                boxes_o[r * 4 + 0] = box[0];
                boxes_o[r * 4 + 1] = box[1];
                boxes_o[r * 4 + 2] = box[2];
                boxes_o[r * 4 + 3] = box[3];
                scores_o[r] = s;
                labels_o[r] = (float)c;
            }
        }
        // default-fill the remaining slots (disjoint from rank writers)
        int start = (L < DETS) ? L : DETS;
        for (int r = tid; r < DETS; r += 256) {
            if (r >= start) {
                boxes_o[r * 4 + 0] = 0.0f;
                boxes_o[r * 4 + 1] = 0.0f;
                boxes_o[r * 4 + 2] = 0.0f;
                boxes_o[r * 4 + 3] = 0.0f;
                scores_o[r] = 0.0f;
                labels_o[r] = -1.0f;
            }
        }
    } else {
        // pathological fallback: repeated argmax over global list (correct, slow)
        for (int it = 0; it < DETS; ++it) {
            float bs = NEG_INF; int bf = 0x7fffffff; int bp = -1;
            for (int i = tid; i < M; i += 256) {
                float s = cs[i]; int f = ci[i];
                if (s > bs || (s == bs && f < bf)) { bs = s; bf = f; bp = i; }
            }
            rs[tid] = bs; rf[tid] = bf; rp[tid] = bp;
            __syncthreads();
            for (int off = 128; off; off >>= 1) {
                if (tid < off) {
                    if (rs[tid + off] > rs[tid] ||
                        (rs[tid + off] == rs[tid] && rf[tid + off] < rf[tid])) {
                        rs[tid] = rs[tid + off]; rf[tid] = rf[tid + off]; rp[tid] = rp[tid + off];
                    }
                }
                __syncthreads();
            }
            if (tid == 0) {
                float s = rs[0];
                bool valid = s > SCORE_THRESH;
                float box[4] = {0.f, 0.f, 0.f, 0.f};
                float lab = -1.0f, sc = 0.0f;
                if (valid) {
                    int fi = rf[0];
                    int n = fi / NFG;
                    int c = fi % NFG + 1;
                    decode_box(breg, pbox, b * N_ + n, c, box);
                    lab = (float)c; sc = s;
                    cs[rp[0]] = NEG_INF;
                }
                boxes_o[it * 4 + 0] = box[0];
                boxes_o[it * 4 + 1] = box[1];
                boxes_o[it * 4 + 2] = box[2];
                boxes_o[it * 4 + 3] = box[3];
                scores_o[it] = sc;
                labels_o[it] = lab;
            }
            __syncthreads();
        }
    }
}

// ---------------- launch ----------------

extern "C" void kernel_launch(void* const* d_in, const int* in_sizes, int n_in,
                              void* d_out, int out_size, void* d_ws, size_t ws_size,
                              hipStream_t stream) {
    const float* logits = (const float*)d_in[0];   // [2048, 81]
    const float* breg   = (const float*)d_in[1];   // [2048, 324]
    const float* pbox   = (const float*)d_in[2];   // [2048, 4]
    float* out = (float*)d_out;                    // 800 boxes + 200 scores + 200 labels

    float* prob   = (float*)d_ws;                    // 2048*81 floats
    float* cand_s = prob + (size_t)B_ * N_ * C_;     // B*81920 floats
    int*   cand_i = (int*)(cand_s + (size_t)B_ * CAND);
    int*   count  = (int*)(cand_i + (size_t)B_ * CAND);

    softmax_k<<<B_ * N_, 64, 0, stream>>>(logits, prob, count);
    nms_k<<<B_ * NFG, 256, 0, stream>>>(prob, breg, pbox, cand_s, cand_i, count);
    topk_k<<<B_, 256, 0, stream>>>(cand_s, cand_i, count, breg, pbox, out);
}